// Round 11
// baseline (108.218 us; speedup 1.0000x reference)
//
#include <hip/hip_runtime.h>
#include <math.h>

#define ROWLEN 16384
#define BLOCK  256
#define NCHUNK 16             // 16 x float4 = 64 floats / thread; 256*64 = 16384
#define NWAVE  (BLOCK / 64)
#define NMOM   9              // central moments p = 2..10
#define EPSV   1e-10

typedef float f32x2 __attribute__((ext_vector_type(2)));

// VOP3P packed fp32: 2 elements per instruction.
__device__ __forceinline__ f32x2 pk_mul(f32x2 a, f32x2 b)
{
    f32x2 d;
    asm("v_pk_mul_f32 %0, %1, %2" : "=v"(d) : "v"(a), "v"(b));
    return d;
}

// R10 structure (102.7us) with ONE change: VGPR diet to reach 5 blocks/CU
// (512/5 = 102 VGPR cap). The part[] f32x2 array (-18 VGPR) is replaced by
// per-float4 f64 flush -- the R3/R5-proven 4-element flush granularity
// (absmax 0.03125) fed by the R9/R10-proven packed chains. Occupancy was the
// only confirmed-causal lever this session (2->4 blocks: 162->116us).
__global__ __launch_bounds__(BLOCK, 5) void moments_kernel(
    const float* __restrict__ y, float* __restrict__ out)
{
    const int row  = blockIdx.x;
    const int tid  = threadIdx.x;
    const int wave = tid >> 6;
    const int lane = tid & 63;

    const float4* yrow = reinterpret_cast<const float4*>(y + (size_t)row * ROWLEN);

    // ---- single HBM read: keep the whole row in registers ----
    float4 v[NCHUNK];
#pragma unroll
    for (int i = 0; i < NCHUNK; ++i)
        v[i] = yrow[i * BLOCK + tid];

    // ---- phase 1: mean (identical to R5/R9/R10) ----
    double tsum = 0.0;
#pragma unroll
    for (int i = 0; i < NCHUNK; ++i) {
        float s = (v[i].x + v[i].y) + (v[i].z + v[i].w);
        tsum += (double)s;
    }
#pragma unroll
    for (int off = 32; off > 0; off >>= 1)
        tsum += __shfl_xor(tsum, off, 64);

    __shared__ double wsum[NWAVE];
    if (lane == 0) wsum[wave] = tsum;
    __syncthreads();

    double total = 0.0;
#pragma unroll
    for (int w = 0; w < NWAVE; ++w) total += wsum[w];

    const double meand = total * (1.0 / (double)ROWLEN);
    const float  meanf = (float)meand;

    // ---- phase 2: central power sums p=2..10 ----
    // packed-f32 chains, f64 flush per float4 (4 elements)
    double acc[NMOM];
#pragma unroll
    for (int p = 0; p < NMOM; ++p) acc[p] = 0.0;

#pragma unroll
    for (int i = 0; i < NCHUNK; ++i) {
        const float4 c = v[i];
        const f32x2 za = { c.x - meanf, c.y - meanf };
        const f32x2 zb = { c.z - meanf, c.w - meanf };
        f32x2 pa = pk_mul(za, za);              // z^2
        f32x2 pb = pk_mul(zb, zb);
        acc[0] += (double)((pa.x + pa.y) + (pb.x + pb.y));
#pragma unroll
        for (int p = 1; p < NMOM; ++p) {
            pa = pk_mul(pa, za);                // z^(p+2)
            pb = pk_mul(pb, zb);
            acc[p] += (double)((pa.x + pa.y) + (pb.x + pb.y));
        }
    }

    // ---- wave reduce each accumulator (identical to R10) ----
#pragma unroll
    for (int p = 0; p < NMOM; ++p) {
#pragma unroll
        for (int off = 32; off > 0; off >>= 1)
            acc[p] += __shfl_xor(acc[p], off, 64);
    }

    __shared__ double wacc[NWAVE][NMOM];
    if (lane == 0) {
#pragma unroll
        for (int p = 0; p < NMOM; ++p) wacc[wave][p] = acc[p];
    }
    __syncthreads();

    // ---- epilogue: lanes 0..9 in parallel, one output each (as R10) ----
    if (tid < 10) {
        const double N = (double)ROWLEN;
        float* o = out + (size_t)row * 10;

        double s2 = 0.0;
#pragma unroll
        for (int w = 0; w < NWAVE; ++w) s2 += wacc[w][0];
        const double stdv = sqrt(s2 / (N - 1.0)) + EPSV;

        if (tid == 0) {
            // m0: signed log of |mean|, NOT clipped
            const double sg0 = (meand > 0.0) ? 1.0 : (meand < 0.0 ? -1.0 : 0.0);
            o[0] = (float)sg0 * logf((float)(fabs(meand) + EPSV));
        } else {
            const int p = tid - 1;             // moment index 0..8 (orders 2..10)
            double s = 0.0;
#pragma unroll
            for (int w = 0; w < NWAVE; ++w) s += wacc[w][p];

            double sp = stdv;                  // std^1
            for (int k = 0; k <= p; ++k) sp *= stdv;   // std^(p+2)

            const double cm  = s / N;
            const double nrm = cm / (sp + EPSV);
            const double sg  = (nrm > 0.0) ? 1.0 : (nrm < 0.0 ? -1.0 : 0.0);
            float mj = (float)sg * logf((float)(fabs(nrm) + EPSV));
            mj = fminf(10.0f, fmaxf(-10.0f, mj));
            o[tid] = mj;
        }
    }
}

extern "C" void kernel_launch(void* const* d_in, const int* in_sizes, int n_in,
                              void* d_out, int out_size, void* d_ws, size_t ws_size,
                              hipStream_t stream)
{
    const float* y = (const float*)d_in[0];
    float* out = (float*)d_out;
    const int B = in_sizes[0] / ROWLEN;   // 8192 rows
    moments_kernel<<<B, BLOCK, 0, stream>>>(y, out);
}